// Round 12
// baseline (919.665 us; speedup 1.0000x reference)
//
#include <hip/hip_runtime.h>
#include <hip/hip_bf16.h>

typedef __bf16 bf16x8 __attribute__((ext_vector_type(8)));
typedef float  f32x4  __attribute__((ext_vector_type(4)));
typedef unsigned short u16;
typedef unsigned int   u32;
typedef unsigned int   u32x2 __attribute__((ext_vector_type(2)));
typedef unsigned long long u64;

#define NB 1024
#define NS 1024
#define NI 32
#define NH 128
#define NCH (NS / 8)

// byte strides
#define HB_BUF  4352   // one h ping-pong buffer: 16*17*2 u64
#define HB_BUFU 544    // same in u64 units
#define HX_SLOT 1088   // one x step-slot: 4*17*2 u64
#define HX_BUF  8704   // one x chunk buffer: 8 slots

// Pack 4 f32 -> 4 bf16 (RNE) in 2 VALU.
__device__ __forceinline__ u64 pack4_bf16(f32x4 v) {
  u32 lo, hi;
  asm("v_cvt_pk_bf16_f32 %0, %1, %2" : "=v"(lo) : "v"(v[0]), "v"(v[1]));
  asm("v_cvt_pk_bf16_f32 %0, %1, %2" : "=v"(hi) : "v"(v[2]), "v"(v[3]));
  u32x2 p; p[0] = lo; p[1] = hi;
  return __builtin_bit_cast(u64, p);
}

// Fused gate math, 3 trans + 1 clamp per element (az clamps unnecessary:
// e->inf => den->inf => rcp->0 => hn=h, graceful; f needs the +side clamp only).
//   h' = h + [(f-1) - h(f+1)] / [(1+e)(f+1)],  e = e^{-az}, f = e^{2 ah}
__device__ __forceinline__ f32x4 gru_elem(f32x4 az, f32x4 ah, f32x4 h) {
  const float NL2E  = -1.4426950408889634f;
  const float P2L2E =  2.8853900817779268f;
  f32x4 hn;
#pragma unroll
  for (int r = 0; r < 4; ++r) {
    float b   = fminf(ah[r], 15.f);
    float e   = __builtin_amdgcn_exp2f(az[r] * NL2E);
    float f   = __builtin_amdgcn_exp2f(b * P2L2E);
    float fp  = f + 1.f;
    float num = __builtin_fmaf(-h[r], fp, f - 1.f);
    float den = (1.f + e) * fp;
    float rr  = __builtin_amdgcn_rcpf(den);
    hn[r] = __builtin_fmaf(num, rr, h[r]);
  }
  return hn;
}

// Block: 512 threads = TWO independent 16-row chains, 4 waves each (32 cols/wave).
// Wave i and wave i+4 share SIMD i but belong to DIFFERENT chains with SEPARATE
// flag-based sync domains -> the CU scheduler overlaps chain A's MFMA phase with
// chain B's elem/LDS phases (impossible under the block-wide s_barrier).
// Intra-chain sync: flags[chain][wave] = completed-step counter. Producer:
// ds_write h -> lgkmcnt(0) -> flag = t+1. Consumer: poll 4 flags >= t, then read
// (opaque zero 'zz' from the poll is added to read addresses: no hoisting).
// Depth-2 h ping-pong safe: poll >= t implies all waves finished step t-1's reads.
// MFMA: D'[n][m] = sum_k U[k][n] h[m][k]; B'-frag lane l: h[m=l&15][k=32kt+8g+j];
// D' lane l: h_new[m=l&15][n=32wc+16nt+4g+r].  LDS k-major + 17-row pad.
__global__ __launch_bounds__(512, 1) void gru_scan(
    const float* __restrict__ x,
    const float* __restrict__ Wz, const float* __restrict__ Uz, const float* __restrict__ bz,
    const float* __restrict__ Wh, const float* __restrict__ Uh, const float* __restrict__ bh,
    float* __restrict__ out)
{
  __shared__ __align__(16) u64 hb[2][2][16][17][2];     // [chain][buf] 17.4 KB
  __shared__ __align__(16) u64 hx[2][2][8][4][17][2];   // [chain][buf] 34.8 KB
  __shared__ __align__(16) u32 flags[2][4];

  const int tid   = threadIdx.x;
  const int lane  = tid & 63;
  const int w     = tid >> 6;     // wave 0..7
  const int wc    = w & 3;        // wave within chain
  const int chain = w >> 2;       // 0 or 1
  const int ml    = lane & 15;    // batch row in tile
  const int g     = lane >> 4;    // k-group / reg-group
  const int rb    = blockIdx.x * 32 + chain * 16;

  // ---- persistent weight fragments (2 n-tiles per wave) ----
  bf16x8 ufrag[2][2][4];   // [gate][nt][kt]
  bf16x8 wfrag[2][2];      // [gate][nt]
  f32x4  bias2[2][2];      // [gate][nt]
  {
    const float* Ug[2] = {Uz, Uh};
    const float* Wg[2] = {Wz, Wh};
    const float* bg[2] = {bz, bh};
#pragma unroll
    for (int gate = 0; gate < 2; ++gate) {
#pragma unroll
      for (int nt = 0; nt < 2; ++nt) {
        const int n0 = 32 * wc + 16 * nt + ml;
#pragma unroll
        for (int kt = 0; kt < 4; ++kt)
#pragma unroll
          for (int j = 0; j < 8; ++j)
            ufrag[gate][nt][kt][j] = (__bf16)Ug[gate][(32 * kt + 8 * g + j) * NH + n0];
#pragma unroll
        for (int j = 0; j < 8; ++j)
          wfrag[gate][nt][j] = (__bf16)Wg[gate][(8 * g + j) * NH + n0];
        const int nb = 32 * wc + 16 * nt + 4 * g;
#pragma unroll
        for (int r = 0; r < 4; ++r) bias2[gate][nt][r] = bg[gate][nb + r];
      }
    }
  }

  // init: h(0)=0 and flags=0 (per chain)
  const int tc = tid & 255;
  for (int i = tc; i < 16 * 17 * 2; i += 256) ((u64*)&hb[chain][0][0][0][0])[i] = 0ULL;
  if (tc < 4) flags[chain][tc] = 0u;

  // ---- x staging mapping: 256 threads per chain, 16 floats each per chunk ----
  const int r_st  = tc >> 4;
  const int c16   = tc & 15;
  const int tt_st = c16 >> 1;
  const int ku0   = (c16 & 1) * 2;
  const float* xbase = x + (size_t)(rb + r_st) * (NS * NI) + tt_st * NI + (c16 & 1) * 16;

  {  // stage chunk 0
    f32x4 a0 = *(const f32x4*)(xbase);
    f32x4 a1 = *(const f32x4*)(xbase + 4);
    f32x4 a2 = *(const f32x4*)(xbase + 8);
    f32x4 a3 = *(const f32x4*)(xbase + 12);
    bf16x8 u0, u1;
#pragma unroll
    for (int j = 0; j < 4; ++j) {
      u0[j] = (__bf16)a0[j]; u0[4 + j] = (__bf16)a1[j];
      u1[j] = (__bf16)a2[j]; u1[4 + j] = (__bf16)a3[j];
    }
    *(bf16x8*)&hx[chain][0][tt_st][ku0 + 0][r_st][0] = u0;
    *(bf16x8*)&hx[chain][0][tt_st][ku0 + 1][r_st][0] = u1;
  }
  __syncthreads();                                   // once, cold
  if (chain) __builtin_amdgcn_s_sleep(8);            // ~512cy skew: desync the chains

  // ---- per-lane pointers ----
  const char* hbc  = (const char*)&hb[chain][0][0][0][0];
  const char* hro0 = hbc + (((0 * 4 + g) * 34 + ml * 2) << 3);
  const char* hro1 = hbc + (((1 * 4 + g) * 34 + ml * 2) << 3);
  const char* hro2 = hbc + (((2 * 4 + g) * 34 + ml * 2) << 3);
  const char* hro3 = hbc + (((3 * 4 + g) * 34 + ml * 2) << 3);
  u64* hw0 = (u64*)hbc + (4 * wc + 0 + (g >> 1)) * 34 + ml * 2 + (g & 1);
  u64* hw1 = (u64*)hbc + (4 * wc + 2 + (g >> 1)) * 34 + ml * 2 + (g & 1);
  const char* hxro = (const char*)&hx[chain][0][0][0][0][0] + ((g * 34 + ml * 2) << 3);
  char* hxw0 = (char*)&hx[chain][0][0][0][0][0] + tt_st * HX_SLOT + (ku0 + 0) * 272 + r_st * 16;
  char* hxw1 = (char*)&hx[chain][0][0][0][0][0] + tt_st * HX_SLOT + (ku0 + 1) * 272 + r_st * 16;
  volatile u32* fvp = &flags[chain][0];
  volatile u32* fwp = &flags[chain][wc];

  f32x4 hv0 = {0.f, 0.f, 0.f, 0.f};
  f32x4 hv1 = {0.f, 0.f, 0.f, 0.f};
  float* optr = out + (size_t)(rb + ml) * NS * NH + 32 * wc + 4 * g;
  const f32x4 zero4 = {0.f, 0.f, 0.f, 0.f};
  f32x4 vx0, vx1, vx2, vx3;
  int tcur = 0;

  // ax(0)
  f32x4 axz0, axz1, axh0, axh1;
  {
    bf16x8 xf = *(const bf16x8*)hxro;
    axz0 = __builtin_amdgcn_mfma_f32_16x16x32_bf16(wfrag[0][0], xf, bias2[0][0], 0, 0, 0);
    axz1 = __builtin_amdgcn_mfma_f32_16x16x32_bf16(wfrag[0][1], xf, bias2[0][1], 0, 0, 0);
    axh0 = __builtin_amdgcn_mfma_f32_16x16x32_bf16(wfrag[1][0], xf, bias2[1][0], 0, 0, 0);
    axh1 = __builtin_amdgcn_mfma_f32_16x16x32_bf16(wfrag[1][1], xf, bias2[1][1], 0, 0, 0);
  }

  // One step. P = TT&1, XB, TT compile-time. CNEXT = next chunk index (runtime).
#define GRU_STEP(P, XB, TT, MORE, CNEXT)                                                    \
  {                                                                                         \
    /* poll own chain's 4 flags >= tcur (volatile: re-read each iteration) */               \
    u32 fa, fb, fc, fd;                                                                     \
    const u32 tgt = (u32)tcur;                                                              \
    do { fa = fvp[0]; fb = fvp[1]; fc = fvp[2]; fd = fvp[3]; }                              \
    while (fa < tgt || fb < tgt || fc < tgt || fd < tgt);                                   \
    u32 zz;                                                                                 \
    asm("v_and_b32 %0, 0, %1" : "=v"(zz) : "v"(fa | fd));                                   \
    __builtin_amdgcn_sched_barrier(0);                                                      \
    /* h + x fragment reads (addresses carry zz: cannot hoist above the poll) */            \
    bf16x8 hf0 = *(const bf16x8*)(hro0 + zz + (P) * HB_BUF);                                \
    bf16x8 hf1 = *(const bf16x8*)(hro1 + zz + (P) * HB_BUF);                                \
    bf16x8 hf2 = *(const bf16x8*)(hro2 + zz + (P) * HB_BUF);                                \
    bf16x8 hf3 = *(const bf16x8*)(hro3 + zz + (P) * HB_BUF);                                \
    bf16x8 xf  = *(const bf16x8*)(hxro + zz +                                               \
                   (((TT) == 7) ? ((XB) ^ 1) : (XB)) * HX_BUF + (((TT) + 1) & 7) * HX_SLOT);\
    /* issue next-chunk x loads early (TT==0: ~6 steps of cover) */                         \
    if ((TT) == 0 && (MORE)) {                                                              \
      const float* p = xbase + (size_t)(CNEXT) * (8 * NI);                                  \
      vx0 = *(const f32x4*)(p);     vx1 = *(const f32x4*)(p + 4);                           \
      vx2 = *(const f32x4*)(p + 8); vx3 = *(const f32x4*)(p + 12);                          \
    }                                                                                       \
    /* h-MFMAs: 8 independent 2-deep chains */                                              \
    f32x4 cz0a = __builtin_amdgcn_mfma_f32_16x16x32_bf16(ufrag[0][0][0], hf0, axz0, 0,0,0); \
    f32x4 cz1a = __builtin_amdgcn_mfma_f32_16x16x32_bf16(ufrag[0][1][0], hf0, axz1, 0,0,0); \
    f32x4 ch0a = __builtin_amdgcn_mfma_f32_16x16x32_bf16(ufrag[1][0][0], hf0, axh0, 0,0,0); \
    f32x4 ch1a = __builtin_amdgcn_mfma_f32_16x16x32_bf16(ufrag[1][1][0], hf0, axh1, 0,0,0); \
    f32x4 cz0b = __builtin_amdgcn_mfma_f32_16x16x32_bf16(ufrag[0][0][2], hf2, zero4, 0,0,0);\
    f32x4 cz1b = __builtin_amdgcn_mfma_f32_16x16x32_bf16(ufrag[0][1][2], hf2, zero4, 0,0,0);\
    f32x4 ch0b = __builtin_amdgcn_mfma_f32_16x16x32_bf16(ufrag[1][0][2], hf2, zero4, 0,0,0);\
    f32x4 ch1b = __builtin_amdgcn_mfma_f32_16x16x32_bf16(ufrag[1][1][2], hf2, zero4, 0,0,0);\
    cz0a = __builtin_amdgcn_mfma_f32_16x16x32_bf16(ufrag[0][0][1], hf1, cz0a, 0, 0, 0);     \
    cz1a = __builtin_amdgcn_mfma_f32_16x16x32_bf16(ufrag[0][1][1], hf1, cz1a, 0, 0, 0);     \
    ch0a = __builtin_amdgcn_mfma_f32_16x16x32_bf16(ufrag[1][0][1], hf1, ch0a, 0, 0, 0);     \
    ch1a = __builtin_amdgcn_mfma_f32_16x16x32_bf16(ufrag[1][1][1], hf1, ch1a, 0, 0, 0);     \
    cz0b = __builtin_amdgcn_mfma_f32_16x16x32_bf16(ufrag[0][0][3], hf3, cz0b, 0, 0, 0);     \
    cz1b = __builtin_amdgcn_mfma_f32_16x16x32_bf16(ufrag[0][1][3], hf3, cz1b, 0, 0, 0);     \
    ch0b = __builtin_amdgcn_mfma_f32_16x16x32_bf16(ufrag[1][0][3], hf3, ch0b, 0, 0, 0);     \
    ch1b = __builtin_amdgcn_mfma_f32_16x16x32_bf16(ufrag[1][1][3], hf3, ch1b, 0, 0, 0);     \
    /* ax(t+1) */                                                                           \
    axz0 = __builtin_amdgcn_mfma_f32_16x16x32_bf16(wfrag[0][0], xf, bias2[0][0], 0, 0, 0);  \
    axz1 = __builtin_amdgcn_mfma_f32_16x16x32_bf16(wfrag[0][1], xf, bias2[0][1], 0, 0, 0);  \
    axh0 = __builtin_amdgcn_mfma_f32_16x16x32_bf16(wfrag[1][0], xf, bias2[1][0], 0, 0, 0);  \
    axh1 = __builtin_amdgcn_mfma_f32_16x16x32_bf16(wfrag[1][1], xf, bias2[1][1], 0, 0, 0);  \
    const f32x4 az0 = cz0a + cz0b;                                                          \
    const f32x4 az1 = cz1a + cz1b;                                                          \
    const f32x4 ah0 = ch0a + ch0b;                                                          \
    const f32x4 ah1 = ch1a + ch1b;                                                          \
    f32x4 hn0 = gru_elem(az0, ah0, hv0);                                                    \
    f32x4 hn1 = gru_elem(az1, ah1, hv1);                                                    \
    hv0 = hn0; hv1 = hn1;                                                                   \
    /* publish bf16 h(t+1) */                                                               \
    hw0[(P ^ 1) * HB_BUFU] = pack4_bf16(hn0);                                               \
    hw1[(P ^ 1) * HB_BUFU] = pack4_bf16(hn1);                                               \
    if ((TT) == 6 && (MORE)) {  /* stage next x chunk */                                    \
      bf16x8 u0, u1;                                                                        \
      _Pragma("unroll")                                                                     \
      for (int j = 0; j < 4; ++j) {                                                         \
        u0[j] = (__bf16)vx0[j]; u0[4 + j] = (__bf16)vx1[j];                                 \
        u1[j] = (__bf16)vx2[j]; u1[4 + j] = (__bf16)vx3[j];                                 \
      }                                                                                     \
      *(bf16x8*)(hxw0 + ((XB) ^ 1) * HX_BUF) = u0;                                          \
      *(bf16x8*)(hxw1 + ((XB) ^ 1) * HX_BUF) = u1;                                          \
    }                                                                                       \
    /* stream outputs (stay in flight; never vmcnt-drained) */                              \
    __builtin_nontemporal_store(hn0, (f32x4*)optr);                                         \
    __builtin_nontemporal_store(hn1, (f32x4*)(optr + 16));                                  \
    optr += NH;                                                                             \
    /* retire LDS writes, then publish flag */                                              \
    asm volatile("s_waitcnt lgkmcnt(0)" ::: "memory");                                      \
    __builtin_amdgcn_sched_barrier(0);                                                      \
    if (lane == 0) *fwp = (u32)(tcur + 1);                                                  \
    ++tcur;                                                                                 \
  }

#define CHUNK_BODY(XB, MORE, CNEXT)                                                         \
    GRU_STEP(0, XB, 0, (MORE), (CNEXT))                                                     \
    GRU_STEP(1, XB, 1, (MORE), (CNEXT))                                                     \
    GRU_STEP(0, XB, 2, (MORE), (CNEXT))                                                     \
    GRU_STEP(1, XB, 3, (MORE), (CNEXT))                                                     \
    GRU_STEP(0, XB, 4, (MORE), (CNEXT))                                                     \
    GRU_STEP(1, XB, 5, (MORE), (CNEXT))                                                     \
    GRU_STEP(0, XB, 6, (MORE), (CNEXT))                                                     \
    GRU_STEP(1, XB, 7, (MORE), (CNEXT))

  for (int cp = 0; cp < NCH; cp += 2) {
    const bool m1 = (cp + 2 < NCH);
    CHUNK_BODY(0, true, cp + 1)   // even chunk: chunk cp+1 always exists
    CHUNK_BODY(1, m1,   cp + 2)   // odd chunk
  }

  // h_last
  const size_t lbase = (size_t)NB * NS * NH + (size_t)(rb + ml) * NH + 32 * wc + 4 * g;
  *(f32x4*)(out + lbase)      = hv0;
  *(f32x4*)(out + lbase + 16) = hv1;
}

extern "C" void kernel_launch(void* const* d_in, const int* in_sizes, int n_in,
                              void* d_out, int out_size, void* d_ws, size_t ws_size,
                              hipStream_t stream) {
  const float* x  = (const float*)d_in[0];
  // d_in[1..3] = W_r, U_r, b_r: unused (r gate never affects the output)
  const float* Wz = (const float*)d_in[4];
  const float* Uz = (const float*)d_in[5];
  const float* bz = (const float*)d_in[6];
  const float* Wh = (const float*)d_in[7];
  const float* Uh = (const float*)d_in[8];
  const float* bh = (const float*)d_in[9];
  float* out = (float*)d_out;

  gru_scan<<<dim3(NB / 32), dim3(512), 0, stream>>>(x, Wz, Uz, bz, Wh, Uh, bh, out);
}

// Round 13
// 424.861 us; speedup vs baseline: 2.1646x; 2.1646x over previous
//
#include <hip/hip_runtime.h>
#include <hip/hip_bf16.h>

typedef __bf16 bf16x8 __attribute__((ext_vector_type(8)));
typedef float  f32x4  __attribute__((ext_vector_type(4)));
typedef unsigned short u16;
typedef unsigned int   u32;
typedef unsigned int   u32x2 __attribute__((ext_vector_type(2)));
typedef unsigned int   u32x4 __attribute__((ext_vector_type(4)));
typedef unsigned long long u64;

#define NB 1024
#define NS 1024
#define NI 32
#define NH 128
#define NCH (NS / 8)

// Pack 4 f32 -> 4 bf16 (RNE) in 2 VALU.
__device__ __forceinline__ u64 pack4_bf16(f32x4 v) {
  u32 lo, hi;
  asm("v_cvt_pk_bf16_f32 %0, %1, %2" : "=v"(lo) : "v"(v[0]), "v"(v[1]));
  asm("v_cvt_pk_bf16_f32 %0, %1, %2" : "=v"(hi) : "v"(v[2]), "v"(v[3]));
  u32x2 p; p[0] = lo; p[1] = hi;
  return __builtin_bit_cast(u64, p);
}

// Pack 8 f32 -> bf16x8 (RNE) in 4 VALU.
__device__ __forceinline__ bf16x8 cvt8pk(f32x4 a, f32x4 b) {
  u32x4 p;
  asm("v_cvt_pk_bf16_f32 %0, %1, %2" : "=v"(p[0]) : "v"(a[0]), "v"(a[1]));
  asm("v_cvt_pk_bf16_f32 %0, %1, %2" : "=v"(p[1]) : "v"(a[2]), "v"(a[3]));
  asm("v_cvt_pk_bf16_f32 %0, %1, %2" : "=v"(p[2]) : "v"(b[0]), "v"(b[1]));
  asm("v_cvt_pk_bf16_f32 %0, %1, %2" : "=v"(p[3]) : "v"(b[2]), "v"(b[3]));
  return __builtin_bit_cast(bf16x8, p);
}

// Barrier that drains lgkmcnt only (no vmcnt): global stores stay in flight.
__device__ __forceinline__ void lds_barrier() {
  __builtin_amdgcn_sched_barrier(0);
  asm volatile("s_waitcnt lgkmcnt(0)" ::: "memory");
  __builtin_amdgcn_s_barrier();
  asm volatile("" ::: "memory");
  __builtin_amdgcn_sched_barrier(0);
}

// Block: 512 threads = 8 waves (2/SIMD). Block owns 16 batch rows for the scan.
// Wave w computes hidden cols [16w, 16w+16).   (R11 skeleton = best known.)
// MFMA: D'[n][m] = sum_k U[k][n] * h[m][k]  (A' = U^T slice, B' = h^T)
//   B'-frag: lane l holds h[m=l&15][k = 32kt + 8(l>>4) + j]   (one ds_read_b128)
//   D'     : lane l holds h_new[m=l&15][n = 16w + 4(l>>4) + r]
// h ping-pongs in LDS as bf16, u64 units swizzled by unit ^ ((row&7)<<1).
// EXP-SCALE FOLD: z-gate weights/bias pre-scaled by -log2(e), h-gate by 2*log2(e),
// so the MFMA outputs are exp2-ready: e = exp2(az'), f = exp2(min(ah', 43.35)).
//   h' = h + [(f-1) - h(f+1)] / [(1+e)(f+1)]    (3 trans; verified absmax 0.0099)
// az' needs no clamp: e->inf => den->inf => rcp->0 => h'=h (graceful saturation).
__global__ __launch_bounds__(512, 2) void gru_scan(
    const float* __restrict__ x,
    const float* __restrict__ Wz, const float* __restrict__ Uz, const float* __restrict__ bz,
    const float* __restrict__ Wh, const float* __restrict__ Uh, const float* __restrict__ bh,
    float* __restrict__ out)
{
  __shared__ __align__(16) u64    hbuf[2][16][32];       // 8 KB
  __shared__ __align__(16) bf16x8 xbuf[2][8][16][4];     // 16 KB

  const int tid  = threadIdx.x;
  const int lane = tid & 63;
  const int w    = tid >> 6;     // wave 0..7
  const int ml   = lane & 15;    // batch row in tile
  const int g    = lane >> 4;    // k-group / reg-group
  const int rb   = blockIdx.x * 16;

  // ---- persistent weight fragments, pre-scaled per gate ----
  bf16x8 ufrag[2][4];   // [gate][kt]
  bf16x8 wfrag[2];      // [gate]
  f32x4  bias2[2];      // [gate], D layout
  {
    const float* Ug[2] = {Uz, Uh};
    const float* Wg[2] = {Wz, Wh};
    const float* bg[2] = {bz, bh};
    const float  gs[2] = {-1.4426950408889634f, 2.8853900817779268f};
    const int n0 = 16 * w + ml;   // A'-row = hidden col
#pragma unroll
    for (int gate = 0; gate < 2; ++gate) {
#pragma unroll
      for (int kt = 0; kt < 4; ++kt)
#pragma unroll
        for (int j = 0; j < 8; ++j)
          ufrag[gate][kt][j] = (__bf16)(Ug[gate][(32 * kt + 8 * g + j) * NH + n0] * gs[gate]);
#pragma unroll
      for (int j = 0; j < 8; ++j)
        wfrag[gate][j] = (__bf16)(Wg[gate][(8 * g + j) * NH + n0] * gs[gate]);
      const int nb = 16 * w + 4 * g;
#pragma unroll
      for (int r = 0; r < 4; ++r) bias2[gate][r] = bg[gate][nb + r] * gs[gate];
    }
  }

  // h0 = 0
  for (int i = tid; i < 16 * 32; i += 512) hbuf[0][i >> 5][i & 31] = 0ULL;

  // ---- x staging: thread (r_st, c8) handles 8 consecutive floats (one 16B unit) ----
  const int r_st  = tid >> 5;          // 0..15
  const int c8    = tid & 31;          // 0..31 -> tt = c8>>2, unit = c8&3
  const int tt_st = c8 >> 2;
  const int un_st = (c8 & 3) ^ (r_st & 3);
  const float* xbase = x + (size_t)(rb + r_st) * (NS * NI) + c8 * 8;

  {  // stage chunk 0
    f32x4 a0 = *(const f32x4*)(xbase);
    f32x4 a1 = *(const f32x4*)(xbase + 4);
    xbuf[0][tt_st][r_st][un_st] = cvt8pk(a0, a1);
  }
  __syncthreads();   // cold path: full drain fine

  // per-lane LDS constants
  const int sw = (ml & 7) << 1;
  int ridx[4];
#pragma unroll
  for (int kt = 0; kt < 4; ++kt) ridx[kt] = (8 * kt + 2 * g) ^ sw;  // even -> b128 ok
  const int widx = (4 * w + g) ^ sw;
  const int xidx = g ^ (ml & 3);

  f32x4 hv = {0.f, 0.f, 0.f, 0.f};
  float* optr = out + (size_t)(rb + ml) * NS * NH + 16 * w + 4 * g;

  f32x4 vxa, vxb;  // x global prefetch regs
  const f32x4 one4   = {1.f, 1.f, 1.f, 1.f};
  const f32x4 clamp4 = {43.35f, 43.35f, 43.35f, 43.35f};   // 15.02 * 2*log2(e)

  // ax (= scaled bias + x@W') for t = 0
  f32x4 axz, axh;
  {
    bf16x8 xf = xbuf[0][0][ml][xidx];
    axz = __builtin_amdgcn_mfma_f32_16x16x32_bf16(wfrag[0], xf, bias2[0], 0, 0, 0);
    axh = __builtin_amdgcn_mfma_f32_16x16x32_bf16(wfrag[1], xf, bias2[1], 0, 0, 0);
  }

  // One step. P, XB, TT all compile-time. Consumes ax(t); produces ax(t+1).
#define GRU_STEP(P, XB, TT, DO_STORE, DO_STAGE)                                            \
  {                                                                                        \
    /* post-barrier read burst: 4 h frags (t) + 1 x frag (t+1) */                          \
    const u64* hrow = &hbuf[P][ml][0];                                                     \
    bf16x8 hf0 = *(const bf16x8*)(hrow + ridx[0]);                                         \
    bf16x8 hf1 = *(const bf16x8*)(hrow + ridx[1]);                                         \
    bf16x8 hf2 = *(const bf16x8*)(hrow + ridx[2]);                                         \
    bf16x8 hf3 = *(const bf16x8*)(hrow + ridx[3]);                                         \
    bf16x8 xf  = xbuf[((TT) == 7) ? ((XB) ^ 1) : (XB)][((TT) + 1) & 7][ml][xidx];          \
    /* h-MFMAs: 2 chains, 4-deep accumulation (throughput-bound; no tail adds) */          \
    f32x4 cz = __builtin_amdgcn_mfma_f32_16x16x32_bf16(ufrag[0][0], hf0, axz, 0, 0, 0);    \
    f32x4 ch = __builtin_amdgcn_mfma_f32_16x16x32_bf16(ufrag[1][0], hf0, axh, 0, 0, 0);    \
    cz = __builtin_amdgcn_mfma_f32_16x16x32_bf16(ufrag[0][1], hf1, cz, 0, 0, 0);           \
    ch = __builtin_amdgcn_mfma_f32_16x16x32_bf16(ufrag[1][1], hf1, ch, 0, 0, 0);           \
    cz = __builtin_amdgcn_mfma_f32_16x16x32_bf16(ufrag[0][2], hf2, cz, 0, 0, 0);           \
    ch = __builtin_amdgcn_mfma_f32_16x16x32_bf16(ufrag[1][2], hf2, ch, 0, 0, 0);           \
    cz = __builtin_amdgcn_mfma_f32_16x16x32_bf16(ufrag[0][3], hf3, cz, 0, 0, 0);           \
    ch = __builtin_amdgcn_mfma_f32_16x16x32_bf16(ufrag[1][3], hf3, ch, 0, 0, 0);           \
    /* ax(t+1): independent, issues behind the h-chains */                                 \
    axz = __builtin_amdgcn_mfma_f32_16x16x32_bf16(wfrag[0], xf, bias2[0], 0, 0, 0);        \
    axh = __builtin_amdgcn_mfma_f32_16x16x32_bf16(wfrag[1], xf, bias2[1], 0, 0, 0);        \
    /* fused elem, packed-f32 vector algebra + 12 scalar trans */                          \
    f32x4 bcl = __builtin_elementwise_min(ch, clamp4);                                     \
    f32x4 e, f;                                                                            \
    _Pragma("unroll")                                                                      \
    for (int r = 0; r < 4; ++r) {                                                          \
      e[r] = __builtin_amdgcn_exp2f(cz[r]);                                                \
      f[r] = __builtin_amdgcn_exp2f(bcl[r]);                                               \
    }                                                                                      \
    f32x4 fp  = f + one4;                                                                  \
    f32x4 num = (f - one4) - hv * fp;                                                      \
    f32x4 den = (e + one4) * fp;                                                           \
    f32x4 rr;                                                                              \
    _Pragma("unroll")                                                                      \
    for (int r = 0; r < 4; ++r) rr[r] = __builtin_amdgcn_rcpf(den[r]);                     \
    f32x4 hn = num * rr + hv;                                                              \
    hv = hn;                                                                               \
    /* publish bf16 h(t+1) FIRST (critical for next step's ds_read) */                     \
    hbuf[P ^ 1][ml][widx] = pack4_bf16(hn);                                                \
    if (DO_STAGE) {  /* convert + write next x chunk (compile-time XB^1) */                \
      xbuf[(XB) ^ 1][tt_st][r_st][un_st] = cvt8pk(vxa, vxb);                               \
    }                                                                                      \
    /* stream hidden_seq[b, t, :] — stays in flight across the barrier */                  \
    if (DO_STORE) { __builtin_nontemporal_store(hn, (f32x4*)optr); optr += NH; }           \
    lds_barrier();                                                                         \
  }

  // Chunk body: XB compile-time; loads issued at tt0, staged at tt6.
#define CHUNK_BODY(XB, CHUNK, MORE)                                                        \
  {                                                                                        \
    if (MORE) {                                                                            \
      const float* p = xbase + (size_t)((CHUNK) + 1) * (8 * NI);                           \
      vxa = *(const f32x4*)(p); vxb = *(const f32x4*)(p + 4);                              \
    }                                                                                      \
    GRU_STEP(0, XB, 0, true, false)                                                        \
    GRU_STEP(1, XB, 1, true, false)                                                        \
    GRU_STEP(0, XB, 2, true, false)                                                        \
    GRU_STEP(1, XB, 3, true, false)                                                        \
    GRU_STEP(0, XB, 4, true, false)                                                        \
    GRU_STEP(1, XB, 5, true, false)                                                        \
    GRU_STEP(0, XB, 6, true, (MORE))                                                       \
    GRU_STEP(1, XB, 7, true, false)                                                        \
  }

  for (int cp = 0; cp < NCH / 2; ++cp) {
    const int  c0 = 2 * cp;
    const bool m1 = (c0 + 2 < NCH);
    CHUNK_BODY(0, c0,     true)   // even chunk: chunk+1 always exists
    CHUNK_BODY(1, c0 + 1, m1)     // odd chunk
  }

  // h_last
  const size_t lbase = (size_t)NB * NS * NH + (size_t)(rb + ml) * NH + 16 * w + 4 * g;
  *(f32x4*)(out + lbase) = hv;
}

extern "C" void kernel_launch(void* const* d_in, const int* in_sizes, int n_in,
                              void* d_out, int out_size, void* d_ws, size_t ws_size,
                              hipStream_t stream) {
  const float* x  = (const float*)d_in[0];
  // d_in[1..3] = W_r, U_r, b_r: unused (r gate never affects the output)
  const float* Wz = (const float*)d_in[4];
  const float* Uz = (const float*)d_in[5];
  const float* bz = (const float*)d_in[6];
  const float* Wh = (const float*)d_in[7];
  const float* Uh = (const float*)d_in[8];
  const float* bh = (const float*)d_in[9];
  float* out = (float*)d_out;

  gru_scan<<<dim3(NB / 16), dim3(512), 0, stream>>>(x, Wz, Uz, bz, Wh, Uh, bh, out);
}